// Round 15
// baseline (123.604 us; speedup 1.0000x reference)
//
#include <hip/hip_runtime.h>
#include <hip/hip_bf16.h>

typedef unsigned short ushortT;
typedef __bf16 bf16x8 __attribute__((ext_vector_type(8)));
typedef float f32x4 __attribute__((ext_vector_type(4)));

#define T_SEQ 2048
#define DH 64
#define NH 16
#define DM 1024
#define TD 3072
#define BATCH 2
#define LOG2E 1.44269504f

#define BARRIER()   asm volatile("s_barrier" ::: "memory")
#define VMCNT(n)    asm volatile("s_waitcnt vmcnt(" #n ")" ::: "memory")

__device__ inline ushortT f2bf(float f){
    union { float f; unsigned int u; } a; a.f = f;
    unsigned int r = a.u + 0x7fffu + ((a.u >> 16) & 1u);
    return (ushortT)(r >> 16);
}
__device__ inline float bf2f(ushortT u){
    union { float f; unsigned int u; } a; a.u = ((unsigned int)u) << 16;
    return a.f;
}

__device__ inline void gload_lds16(const void* g, void* l){
    __builtin_amdgcn_global_load_lds((const __attribute__((address_space(1))) void*)g,
                                     (__attribute__((address_space(3))) void*)l, 16, 0, 0);
}

// ---------------- merged prep: cast x + transcast Wqkv + transcast Wout + Wg ----------------
// blocks [0,4096): cast x; [4096,4864): Wqkv^T; [4864,5120): Wout^T; [5120,5136): Wg^T
__global__ __launch_bounds__(256) void prep_kernel(const float* __restrict__ x,
                                                   ushortT* __restrict__ xbf,
                                                   const float* __restrict__ Wqkv,
                                                   ushortT* __restrict__ wqkvT,
                                                   const float* __restrict__ Wout,
                                                   ushortT* __restrict__ woutT,
                                                   const float* __restrict__ Wg,
                                                   ushortT* __restrict__ wgT){
    __shared__ float tile[64][65];
    int blk = blockIdx.x, tid = threadIdx.x;
    if (blk < 4096){
        int i = (blk * 256 + tid) * 4;
        float4 v = *(const float4*)&x[i];
        xbf[i+0] = f2bf(v.x); xbf[i+1] = f2bf(v.y);
        xbf[i+2] = f2bf(v.z); xbf[i+3] = f2bf(v.w);
        return;
    }
    int c = tid & 63, r4 = tid >> 6;
    if (blk >= 5120){                       // Wg: [h][d][e] -> [h][e][d] bf16
        int h = blk - 5120;
#pragma unroll
        for (int i = 0; i < 16; i++){
            int d = r4 + i*4;
            tile[d][c] = Wg[h*4096 + d*64 + c];
        }
        __syncthreads();
#pragma unroll
        for (int i = 0; i < 16; i++){
            int e = r4 + i*4;
            wgT[h*4096 + e*64 + c] = f2bf(tile[c][e]);
        }
        return;
    }
    const float* in; ushortT* out; int K, N, n0, k0;
    if (blk < 4864){
        int t = blk - 4096; in = Wqkv; out = wqkvT; K = 1024; N = 3072;
        n0 = (t % 48) * 64; k0 = (t / 48) * 64;
    } else {
        int t = blk - 4864; in = Wout; out = woutT; K = 1024; N = 1024;
        n0 = (t & 15) * 64; k0 = (t >> 4) * 64;
    }
#pragma unroll
    for (int i = 0; i < 16; i++){
        int k = r4 + i * 4;
        tile[k][c] = in[(size_t)(k0 + k) * N + n0 + c];
    }
    __syncthreads();
#pragma unroll
    for (int i = 0; i < 16; i++){
        int n = r4 + i * 4;
        out[(size_t)(n0 + n) * K + k0 + c] = f2bf(tile[c][n]);
    }
}

// ---------------- bf16 MFMA GEMM 128x128 (dbuf + counted vmcnt) ----------------
__device__ inline void store_out(ushortT* C, size_t i, float v){ C[i] = f2bf(v); }
__device__ inline void store_out(float*   C, size_t i, float v){ C[i] = v; }

template <typename OUT>
__global__ __launch_bounds__(256) void gemm_bf16_kernel(const ushortT* __restrict__ A,
                                                        const ushortT* __restrict__ BT,
                                                        const float* __restrict__ bias,
                                                        OUT* __restrict__ C,
                                                        int M, int N, int K){
    __shared__ __align__(16) ushortT As[2][128*32];
    __shared__ __align__(16) ushortT Bs[2][128*32];
    int tid = threadIdx.x;
    int m0 = blockIdx.x * 128;
    int n0 = blockIdx.y * 128;
    int wid = tid >> 6, lane = tid & 63;
    int l15 = lane & 15, g = lane >> 4;
    int wr = wid >> 1, wc = wid & 1;

    f32x4 acc[4][4];
#pragma unroll
    for (int i = 0; i < 4; i++)
#pragma unroll
        for (int j = 0; j < 4; j++) acc[i][j] = (f32x4){0.f,0.f,0.f,0.f};

    int srow = wid * 32 + (lane >> 2);
    int sch  = lane & 3;

#define GSTAGE(buf, k0)                                                                  \
    {                                                                                    \
        _Pragma("unroll")                                                                \
        for (int i_ = 0; i_ < 2; i_++){                                                  \
            int row_ = srow + i_ * 16;                                                   \
            const ushortT* asrc_ = A  + (size_t)(m0 + row_) * K + (k0) + sch * 8;        \
            const ushortT* bsrc_ = BT + (size_t)(n0 + row_) * K + (k0) + sch * 8;        \
            gload_lds16(asrc_, (char*)As[buf] + (wid*2 + i_) * 1024);                    \
            gload_lds16(bsrc_, (char*)Bs[buf] + (wid*2 + i_) * 1024);                    \
        }                                                                                \
    }

    GSTAGE(0, 0);

    int nk = K >> 5;
    for (int kt = 0; kt < nk; kt++){
        int buf = kt & 1;
        BARRIER();
        if (kt + 1 < nk){
            GSTAGE(buf ^ 1, (kt + 1) * 32);
            VMCNT(4);
        } else {
            VMCNT(0);
        }
        BARRIER();

        bf16x8 af[4], bfr[4];
#pragma unroll
        for (int mi = 0; mi < 4; mi++){
            int r = wr*64 + mi*16 + l15;
            af[mi]  = *(const bf16x8*)(As[buf] + r*32 + g*8);
        }
#pragma unroll
        for (int ni = 0; ni < 4; ni++){
            int r = wc*64 + ni*16 + l15;
            bfr[ni] = *(const bf16x8*)(Bs[buf] + r*32 + g*8);
        }
#pragma unroll
        for (int mi = 0; mi < 4; mi++)
#pragma unroll
            for (int ni = 0; ni < 4; ni++)
                acc[mi][ni] = __builtin_amdgcn_mfma_f32_16x16x32_bf16(af[mi], bfr[ni], acc[mi][ni], 0, 0, 0);
    }
#undef GSTAGE

#pragma unroll
    for (int mi = 0; mi < 4; mi++){
#pragma unroll
        for (int jj = 0; jj < 4; jj++){
            int mm = m0 + wr*64 + mi*16 + 4*g + jj;
#pragma unroll
            for (int ni = 0; ni < 4; ni++){
                int nn = n0 + wc*64 + ni*16 + l15;
                float v = acc[mi][ni][jj] + bias[nn];
                store_out(C, (size_t)mm * N + nn, v);
            }
        }
    }
}

// ---------------- gate (MFMA): g=sigmoid(Q @ Wg[h]); VgT[b,h,e,t] = g*v ----------------
__global__ __launch_bounds__(256) void gate_kernel(const ushortT* __restrict__ qkv,
                                                   const ushortT* __restrict__ WgT,
                                                   ushortT* __restrict__ vgT){
    __shared__ __align__(16) ushortT VT[64][72];
    int tblk = blockIdx.x, bh = blockIdx.y;
    int b = bh >> 4, h = bh & 15;
    int tid = threadIdx.x, wid = tid >> 6, lane = tid & 63;
    int l15 = lane & 15, g = lane >> 4;
    int t0 = tblk * 64;
    int tl = wid*16 + l15;

    const ushortT* qrow = qkv + ((size_t)b*T_SEQ + t0 + tl)*TD + h*DH;
    bf16x8 qf0 = *(const bf16x8*)(qrow + 8*g);
    bf16x8 qf1 = *(const bf16x8*)(qrow + 32 + 8*g);

    const ushortT* wbase = WgT + h*4096;
    const ushortT* vrow = qkv + ((size_t)b*T_SEQ + t0 + tl)*TD + 2*DM + h*DH;

#pragma unroll
    for (int ns = 0; ns < 4; ns++){
        int e = ns*16 + l15;
        bf16x8 wf0 = *(const bf16x8*)(wbase + e*64 + 8*g);
        bf16x8 wf1 = *(const bf16x8*)(wbase + e*64 + 32 + 8*g);
        f32x4 z = (f32x4){0.f,0.f,0.f,0.f};
        z = __builtin_amdgcn_mfma_f32_16x16x32_bf16(wf0, qf0, z, 0, 0, 0);
        z = __builtin_amdgcn_mfma_f32_16x16x32_bf16(wf1, qf1, z, 0, 0, 0);
        union { ushortT u[4]; uint2 v; } v4;
        v4.v = *(const uint2*)(vrow + ns*16 + 4*g);
#pragma unroll
        for (int jj = 0; jj < 4; jj++){
            float ex = __builtin_amdgcn_exp2f(-z[jj] * LOG2E);
            float gv = __builtin_amdgcn_rcpf(1.f + ex);
            VT[ns*16 + 4*g + jj][tl] = f2bf(gv * bf2f(v4.u[jj]));
        }
    }
    __syncthreads();
    for (int i = tid; i < 64*8; i += 256){
        int e = i >> 3, c8 = (i & 7) * 8;
        *(uint4*)&vgT[((size_t)bh * DH + e) * T_SEQ + t0 + c8] = *(const uint4*)&VT[e][c8];
    }
}

// ---------------- causal flash attention: KVBLK=128, 32 q-rows/wave ----------------
// Block = 256 thr / 4 waves: waves {0,1} own qblk pA (q-halves 0,1), {2,3} own pB.
// Each wave covers 32 q-rows (2 mi sub-tiles of 16). K and V fragments are read
// from LDS ONCE and reused for both mi -> LDS reads per MFMA halved (32 reads /
// 64 MFMA per 128-kv round). Joint 128-kv online softmax per mi. Register-
// resident P (pi-permuted K rows), O^T PV -> all softmax state lane-local.
struct QS2 {
    bf16x8 qf[2][2];       // [mi][d-half]
    float m_[2], lsum[2];
    f32x4 acc[2][4];       // [mi][nt]
};

__device__ __forceinline__ void proc2x(const ushortT* __restrict__ K0,
                                       const ushortT* __restrict__ V0,
                                       const ushortT* __restrict__ K1,
                                       const ushortT* __restrict__ V1,
                                       QS2& S, int t0, int t1, int myp,
                                       int half, int l15, int g){
    int l7 = l15 & 7;
    f32x4 s[2][8];                         // [mi][T*4+ns]
    __builtin_amdgcn_s_setprio(1);
#pragma unroll
    for (int T = 0; T < 2; T++){
        const ushortT* Kb = T ? K1 : K0;
#pragma unroll
        for (int ns = 0; ns < 4; ns++){
            int kr = ns*16 + l15;
            bf16x8 kf0 = *(const bf16x8*)(Kb + kr*64 + ((g    ) ^ l7)*8);
            bf16x8 kf1 = *(const bf16x8*)(Kb + kr*64 + ((4 + g) ^ l7)*8);
#pragma unroll
            for (int mi = 0; mi < 2; mi++){
                f32x4 z = (f32x4){0.f,0.f,0.f,0.f};
                z = __builtin_amdgcn_mfma_f32_16x16x32_bf16(kf0, S.qf[mi][0], z, 0, 0, 0);
                z = __builtin_amdgcn_mfma_f32_16x16x32_bf16(kf1, S.qf[mi][1], z, 0, 0, 0);
                s[mi][T*4 + ns] = z;
            }
        }
    }
    __builtin_amdgcn_s_setprio(0);

    bool diag0 = (t0 == myp);
    bool inv1  = (t1 > myp);
    bool diag1 = (t1 == myp);
    bf16x8 pa[2][4];                       // [mi][T*2+ks]
#pragma unroll
    for (int mi = 0; mi < 2; mi++){
        int qrel = half*32 + mi*16 + l15;
        if (diag0){
#pragma unroll
            for (int ns = 0; ns < 4; ns++){
                int kb = ((ns & 2) << 4) + 8*g + ((ns & 1) << 2);
#pragma unroll
                for (int jj = 0; jj < 4; jj++)
                    if (kb + jj > qrel) s[mi][ns][jj] = -INFINITY;
            }
        }
        if (inv1){
#pragma unroll
            for (int ns = 0; ns < 4; ns++)
#pragma unroll
                for (int jj = 0; jj < 4; jj++) s[mi][4+ns][jj] = -INFINITY;
        } else if (diag1){
#pragma unroll
            for (int ns = 0; ns < 4; ns++){
                int kb = ((ns & 2) << 4) + 8*g + ((ns & 1) << 2);
#pragma unroll
                for (int jj = 0; jj < 4; jj++)
                    if (kb + jj > qrel) s[mi][4+ns][jj] = -INFINITY;
            }
        }

        float tmax = -INFINITY;
#pragma unroll
        for (int ns = 0; ns < 8; ns++){
            float a = fmaxf(s[mi][ns][0], s[mi][ns][1]);
            float c = fmaxf(s[mi][ns][2], s[mi][ns][3]);
            tmax = fmaxf(tmax, fmaxf(a, c));
        }
        tmax = fmaxf(tmax, __shfl_xor(tmax, 16, 64));
        tmax = fmaxf(tmax, __shfl_xor(tmax, 32, 64));

        float mnew = fmaxf(S.m_[mi], tmax);
        float mc = mnew * LOG2E;
        float rs = 0.f;
#pragma unroll
        for (int pr = 0; pr < 4; pr++){
#pragma unroll
            for (int jj = 0; jj < 4; jj++){
                float p0 = __builtin_amdgcn_exp2f(fmaf(s[mi][2*pr  ][jj], LOG2E, -mc));
                float p1 = __builtin_amdgcn_exp2f(fmaf(s[mi][2*pr+1][jj], LOG2E, -mc));
                rs += p0 + p1;
                pa[mi][pr][jj]   = (__bf16)p0;
                pa[mi][pr][4+jj] = (__bf16)p1;
            }
        }
        rs += __shfl_xor(rs, 16, 64);
        rs += __shfl_xor(rs, 32, 64);

        if (!__all(mnew == S.m_[mi])){
            float alpha = __builtin_amdgcn_exp2f(fmaf(S.m_[mi], LOG2E, -mc));
#pragma unroll
            for (int nt = 0; nt < 4; nt++)
#pragma unroll
                for (int jj = 0; jj < 4; jj++) S.acc[mi][nt][jj] *= alpha;
            S.lsum[mi] *= alpha;
            S.m_[mi] = mnew;
        }
        S.lsum[mi] += rs;
    }

    __builtin_amdgcn_s_setprio(1);
#pragma unroll
    for (int T = 0; T < 2; T++){
        if (T == 1 && inv1) break;
        const ushortT* Vb = T ? V1 : V0;
#pragma unroll
        for (int ks = 0; ks < 2; ks++){
#pragma unroll
            for (int nt = 0; nt < 4; nt++){
                bf16x8 vf = *(const bf16x8*)(Vb + (nt*16 + l15)*64 + ((ks*4 + g) ^ l7)*8);
#pragma unroll
                for (int mi = 0; mi < 2; mi++)
                    S.acc[mi][nt] = __builtin_amdgcn_mfma_f32_16x16x32_bf16(
                        vf, pa[mi][T*2 + ks], S.acc[mi][nt], 0, 0, 0);
            }
        }
    }
    __builtin_amdgcn_s_setprio(0);
}

__global__ __launch_bounds__(256, 2) void attn_kernel(const ushortT* __restrict__ qkv,
                                                      const ushortT* __restrict__ vgT,
                                                      ushortT* __restrict__ obf){
    __shared__ __align__(16) ushortT Ks[2][2][64*64];   // [dbuf][tile] 32 KB
    __shared__ __align__(16) ushortT Vs[2][2][64*64];   // 32 KB
    int bh = blockIdx.x, y = blockIdx.y;
    int pairid = (y < 8) ? y : 23 - y;      // co-resident blocks balanced
    int b = bh >> 4, h = bh & 15;
    int tid = threadIdx.x, wid = tid >> 6, lane = tid & 63;
    int l15 = lane & 15, g = lane >> 4;
    int grp  = wid >> 1;                    // 0: qblk pA, 1: qblk pB
    int half = wid & 1;                     // q-half within qblk (32 rows)

    const ushortT* Kg = qkv + (size_t)b * T_SEQ * TD + DM + h * DH;
    const ushortT* Vg = vgT + (size_t)bh * DH * T_SEQ;

    int pA = pairid, pB = 31 - pairid;
    int myp = grp ? pB : pA;

    // staging: 256 thr x 16B x 2 issues per tile; 4 tiles (K0,K1,V0,V1)/round
    int sr0 = tid >> 3;                     // 0..31 (+32 on 2nd issue)
    int sc0 = tid & 7;

#define STAGE_ROUND(buf, rr)                                                             \
    {                                                                                    \
        int t0_ = 2*(rr);     if (t0_ > pB) t0_ = pB;                                    \
        int t1_ = 2*(rr) + 1; if (t1_ > pB) t1_ = pB;                                    \
        _Pragma("unroll")                                                                \
        for (int i_ = 0; i_ < 2; i_++){                                                  \
            int row_  = sr0 + i_*32;                                                     \
            int sc_   = sc0 ^ (row_ & 7);                                                \
            int prow_ = (row_ & 0x20) | ((row_ & 0x0C) << 1) |                           \
                        ((row_ & 0x10) >> 2) | (row_ & 3);                               \
            gload_lds16(Kg + (size_t)(t0_*64 + prow_) * TD + sc_*8,                      \
                        (char*)Ks[buf][0] + tid*16 + i_*4096);                           \
            gload_lds16(Kg + (size_t)(t1_*64 + prow_) * TD + sc_*8,                      \
                        (char*)Ks[buf][1] + tid*16 + i_*4096);                           \
            gload_lds16(Vg + (size_t)row_ * T_SEQ + t0_*64 + sc_*8,                      \
                        (char*)Vs[buf][0] + tid*16 + i_*4096);                           \
            gload_lds16(Vg + (size_t)row_ * T_SEQ + t1_*64 + sc_*8,                      \
                        (char*)Vs[buf][1] + tid*16 + i_*4096);                           \
        }                                                                                \
    }

    QS2 S;
#pragma unroll
    for (int mi = 0; mi < 2; mi++){
        int qrow = myp*64 + half*32 + mi*16 + l15;
        const ushortT* qb = qkv + ((size_t)b * T_SEQ + qrow) * TD + h * DH;
        S.qf[mi][0] = *(const bf16x8*)(qb + 8*g);
        S.qf[mi][1] = *(const bf16x8*)(qb + 32 + 8*g);
#pragma unroll
        for (int j = 0; j < 8; j++){
            S.qf[mi][0][j] = (__bf16)((float)S.qf[mi][0][j] * 0.125f);
            S.qf[mi][1][j] = (__bf16)((float)S.qf[mi][1][j] * 0.125f);
        }
        S.m_[mi] = -INFINITY; S.lsum[mi] = 0.f;
#pragma unroll
        for (int nt = 0; nt < 4; nt++) S.acc[mi][nt] = (f32x4){0.f,0.f,0.f,0.f};
    }

    int nr = (33 - pairid) >> 1;            // ceil((pB+1)/2)
    STAGE_ROUND(0, 0);

    for (int r = 0; r < nr; r++){
        int buf = r & 1;
        BARRIER();                          // all waves done reading buf^1
        if (r + 1 < nr){
            STAGE_ROUND(buf ^ 1, r + 1);    // 8 loads stay in flight across barrier
            VMCNT(8);
        } else {
            VMCNT(0);
        }
        BARRIER();
        int t0 = 2*r;
        if (t0 <= myp)
            proc2x(Ks[buf][0], Vs[buf][0], Ks[buf][1], Vs[buf][1],
                   S, t0, t0 + 1, myp, half, l15, g);
    }
#undef STAGE_ROUND

#pragma unroll
    for (int mi = 0; mi < 2; mi++){
        float inv = 1.f / S.lsum[mi];
        size_t orow = ((size_t)b * T_SEQ + myp*64 + half*32 + mi*16 + l15) * DM + h*DH;
#pragma unroll
        for (int nt = 0; nt < 4; nt++){
            union { ushortT u[4]; uint2 v; } pk;
#pragma unroll
            for (int jj = 0; jj < 4; jj++) pk.u[jj] = f2bf(S.acc[mi][nt][jj] * inv);
            *(uint2*)&obf[orow + nt*16 + 4*g] = pk.v;
        }
    }
}

extern "C" void kernel_launch(void* const* d_in, const int* in_sizes, int n_in,
                              void* d_out, int out_size, void* d_ws, size_t ws_size,
                              hipStream_t stream){
    const float* x    = (const float*)d_in[0];
    const float* Wqkv = (const float*)d_in[1];
    const float* bqkv = (const float*)d_in[2];
    const float* Wg   = (const float*)d_in[3];
    const float* Wout = (const float*)d_in[4];
    const float* bout = (const float*)d_in[5];

    char* ws = (char*)d_ws;
    ushortT* xbf   = (ushortT*)(ws);                 //  8 MB : (4096,1024) bf16
    ushortT* wqkvT = (ushortT*)(ws + 8388608);       //  6 MB : (3072,1024) bf16
    ushortT* woutT = (ushortT*)(ws + 14680064);      //  2 MB : (1024,1024) bf16
    ushortT* qkvb  = (ushortT*)(ws + 16777216);      // 24 MB : (4096,3072) bf16
    ushortT* vgT   = (ushortT*)(ws + 41943040);      //  8 MB : (32,64,2048) bf16
    ushortT* obf   = (ushortT*)(ws + 50331648);      //  8 MB : (4096,1024) bf16
    ushortT* wgT   = (ushortT*)(ws + 58720256);      // 128KB : (16,64,64) bf16

    prep_kernel<<<5136, 256, 0, stream>>>(x, xbf, Wqkv, wqkvT, Wout, woutT, Wg, wgT);
    gemm_bf16_kernel<ushortT><<<dim3(32,24), 256, 0, stream>>>(xbf, wqkvT, bqkv, qkvb, 4096, 3072, 1024);
    gate_kernel<<<dim3(32,32), 256, 0, stream>>>(qkvb, wgT, vgT);
    attn_kernel<<<dim3(32,16), 256, 0, stream>>>(qkvb, vgT, obf);
    gemm_bf16_kernel<float><<<dim3(32,8), 256, 0, stream>>>(obf, woutT, bout, (float*)d_out, 4096, 1024, 1024);
}

// Round 16
// 109.973 us; speedup vs baseline: 1.1239x; 1.1239x over previous
//
#include <hip/hip_runtime.h>
#include <hip/hip_bf16.h>

typedef unsigned short ushortT;
typedef __bf16 bf16x8 __attribute__((ext_vector_type(8)));
typedef float f32x4 __attribute__((ext_vector_type(4)));

#define T_SEQ 2048
#define DH 64
#define NH 16
#define DM 1024
#define TD 3072
#define BATCH 2
#define LOG2E 1.44269504f

#define BARRIER()   asm volatile("s_barrier" ::: "memory")
#define VMCNT(n)    asm volatile("s_waitcnt vmcnt(" #n ")" ::: "memory")

__device__ inline ushortT f2bf(float f){
    union { float f; unsigned int u; } a; a.f = f;
    unsigned int r = a.u + 0x7fffu + ((a.u >> 16) & 1u);
    return (ushortT)(r >> 16);
}
__device__ inline float bf2f(ushortT u){
    union { float f; unsigned int u; } a; a.u = ((unsigned int)u) << 16;
    return a.f;
}

__device__ inline void gload_lds16(const void* g, void* l){
    __builtin_amdgcn_global_load_lds((const __attribute__((address_space(1))) void*)g,
                                     (__attribute__((address_space(3))) void*)l, 16, 0, 0);
}

// ---------------- merged prep: cast x + transcast Wqkv + transcast Wout + Wg ----------------
__global__ __launch_bounds__(256) void prep_kernel(const float* __restrict__ x,
                                                   ushortT* __restrict__ xbf,
                                                   const float* __restrict__ Wqkv,
                                                   ushortT* __restrict__ wqkvT,
                                                   const float* __restrict__ Wout,
                                                   ushortT* __restrict__ woutT,
                                                   const float* __restrict__ Wg,
                                                   ushortT* __restrict__ wgT){
    __shared__ float tile[64][65];
    int blk = blockIdx.x, tid = threadIdx.x;
    if (blk < 4096){
        int i = (blk * 256 + tid) * 4;
        float4 v = *(const float4*)&x[i];
        xbf[i+0] = f2bf(v.x); xbf[i+1] = f2bf(v.y);
        xbf[i+2] = f2bf(v.z); xbf[i+3] = f2bf(v.w);
        return;
    }
    int c = tid & 63, r4 = tid >> 6;
    if (blk >= 5120){                       // Wg: [h][d][e] -> [h][e][d] bf16
        int h = blk - 5120;
#pragma unroll
        for (int i = 0; i < 16; i++){
            int d = r4 + i*4;
            tile[d][c] = Wg[h*4096 + d*64 + c];
        }
        __syncthreads();
#pragma unroll
        for (int i = 0; i < 16; i++){
            int e = r4 + i*4;
            wgT[h*4096 + e*64 + c] = f2bf(tile[c][e]);
        }
        return;
    }
    const float* in; ushortT* out; int K, N, n0, k0;
    if (blk < 4864){
        int t = blk - 4096; in = Wqkv; out = wqkvT; K = 1024; N = 3072;
        n0 = (t % 48) * 64; k0 = (t / 48) * 64;
    } else {
        int t = blk - 4864; in = Wout; out = woutT; K = 1024; N = 1024;
        n0 = (t & 15) * 64; k0 = (t >> 4) * 64;
    }
#pragma unroll
    for (int i = 0; i < 16; i++){
        int k = r4 + i * 4;
        tile[k][c] = in[(size_t)(k0 + k) * N + n0 + c];
    }
    __syncthreads();
#pragma unroll
    for (int i = 0; i < 16; i++){
        int n = r4 + i * 4;
        out[(size_t)(n0 + n) * K + k0 + c] = f2bf(tile[c][n]);
    }
}

// ---------------- bf16 MFMA GEMM 128x128 (dbuf + counted vmcnt): qkv proj ----------------
__global__ __launch_bounds__(256) void gemm_bf16_kernel(const ushortT* __restrict__ A,
                                                        const ushortT* __restrict__ BT,
                                                        const float* __restrict__ bias,
                                                        ushortT* __restrict__ C,
                                                        int M, int N, int K){
    __shared__ __align__(16) ushortT As[2][128*32];
    __shared__ __align__(16) ushortT Bs[2][128*32];
    int tid = threadIdx.x;
    int m0 = blockIdx.x * 128;
    int n0 = blockIdx.y * 128;
    int wid = tid >> 6, lane = tid & 63;
    int l15 = lane & 15, g = lane >> 4;
    int wr = wid >> 1, wc = wid & 1;

    f32x4 acc[4][4];
#pragma unroll
    for (int i = 0; i < 4; i++)
#pragma unroll
        for (int j = 0; j < 4; j++) acc[i][j] = (f32x4){0.f,0.f,0.f,0.f};

    int srow = wid * 32 + (lane >> 2);
    int sch  = lane & 3;

#define GSTAGE(buf, k0)                                                                  \
    {                                                                                    \
        _Pragma("unroll")                                                                \
        for (int i_ = 0; i_ < 2; i_++){                                                  \
            int row_ = srow + i_ * 16;                                                   \
            const ushortT* asrc_ = A  + (size_t)(m0 + row_) * K + (k0) + sch * 8;        \
            const ushortT* bsrc_ = BT + (size_t)(n0 + row_) * K + (k0) + sch * 8;        \
            gload_lds16(asrc_, (char*)As[buf] + (wid*2 + i_) * 1024);                    \
            gload_lds16(bsrc_, (char*)Bs[buf] + (wid*2 + i_) * 1024);                    \
        }                                                                                \
    }

    GSTAGE(0, 0);

    int nk = K >> 5;
    for (int kt = 0; kt < nk; kt++){
        int buf = kt & 1;
        BARRIER();
        if (kt + 1 < nk){
            GSTAGE(buf ^ 1, (kt + 1) * 32);
            VMCNT(4);
        } else {
            VMCNT(0);
        }
        BARRIER();

        bf16x8 af[4], bfr[4];
#pragma unroll
        for (int mi = 0; mi < 4; mi++){
            int r = wr*64 + mi*16 + l15;
            af[mi]  = *(const bf16x8*)(As[buf] + r*32 + g*8);
        }
#pragma unroll
        for (int ni = 0; ni < 4; ni++){
            int r = wc*64 + ni*16 + l15;
            bfr[ni] = *(const bf16x8*)(Bs[buf] + r*32 + g*8);
        }
#pragma unroll
        for (int mi = 0; mi < 4; mi++)
#pragma unroll
            for (int ni = 0; ni < 4; ni++)
                acc[mi][ni] = __builtin_amdgcn_mfma_f32_16x16x32_bf16(af[mi], bfr[ni], acc[mi][ni], 0, 0, 0);
    }
#undef GSTAGE

#pragma unroll
    for (int mi = 0; mi < 4; mi++){
#pragma unroll
        for (int jj = 0; jj < 4; jj++){
            int mm = m0 + wr*64 + mi*16 + 4*g + jj;
#pragma unroll
            for (int ni = 0; ni < 4; ni++){
                int nn = n0 + wc*64 + ni*16 + l15;
                C[(size_t)mm * N + nn] = f2bf(acc[mi][ni][jj] + bias[nn]);
            }
        }
    }
}

// ---------------- 64x128-tile GEMM (dbuf + counted vmcnt), float out: out proj ----------------
// grid (M/64, N/128) = (64, 8) -> 512 blocks = 2/CU. Waves 2m x 2n, acc[2][4].
__global__ __launch_bounds__(256) void gemm_out_kernel(const ushortT* __restrict__ A,
                                                       const ushortT* __restrict__ BT,
                                                       const float* __restrict__ bias,
                                                       float* __restrict__ C,
                                                       int M, int N, int K){
    __shared__ __align__(16) ushortT As[2][64*32];
    __shared__ __align__(16) ushortT Bs[2][128*32];
    int tid = threadIdx.x;
    int m0 = blockIdx.x * 64;
    int n0 = blockIdx.y * 128;
    int wid = tid >> 6, lane = tid & 63;
    int l15 = lane & 15, g = lane >> 4;
    int wr = wid >> 1, wc = wid & 1;

    f32x4 acc[2][4];
#pragma unroll
    for (int i = 0; i < 2; i++)
#pragma unroll
        for (int j = 0; j < 4; j++) acc[i][j] = (f32x4){0.f,0.f,0.f,0.f};

    int srow = tid >> 2;        // 0..63
    int sch  = tid & 3;

#define GSTAGE(buf, k0)                                                                  \
    {                                                                                    \
        gload_lds16(A + (size_t)(m0 + srow) * K + (k0) + sch * 8,                        \
                    (char*)As[buf] + tid * 16);                                          \
        _Pragma("unroll")                                                                \
        for (int i_ = 0; i_ < 2; i_++){                                                  \
            int row_ = srow + i_ * 64;                                                   \
            gload_lds16(BT + (size_t)(n0 + row_) * K + (k0) + sch * 8,                   \
                        (char*)Bs[buf] + (i_*256 + tid) * 16);                           \
        }                                                                                \
    }

    GSTAGE(0, 0);

    int nk = K >> 5;
    for (int kt = 0; kt < nk; kt++){
        int buf = kt & 1;
        BARRIER();
        if (kt + 1 < nk){
            GSTAGE(buf ^ 1, (kt + 1) * 32);
            VMCNT(3);
        } else {
            VMCNT(0);
        }
        BARRIER();

        bf16x8 af[2], bfr[4];
#pragma unroll
        for (int mi = 0; mi < 2; mi++){
            int r = wr*32 + mi*16 + l15;
            af[mi]  = *(const bf16x8*)(As[buf] + r*32 + g*8);
        }
#pragma unroll
        for (int ni = 0; ni < 4; ni++){
            int r = wc*64 + ni*16 + l15;
            bfr[ni] = *(const bf16x8*)(Bs[buf] + r*32 + g*8);
        }
#pragma unroll
        for (int mi = 0; mi < 2; mi++)
#pragma unroll
            for (int ni = 0; ni < 4; ni++)
                acc[mi][ni] = __builtin_amdgcn_mfma_f32_16x16x32_bf16(af[mi], bfr[ni], acc[mi][ni], 0, 0, 0);
    }
#undef GSTAGE

#pragma unroll
    for (int mi = 0; mi < 2; mi++){
#pragma unroll
        for (int jj = 0; jj < 4; jj++){
            int mm = m0 + wr*32 + mi*16 + 4*g + jj;
#pragma unroll
            for (int ni = 0; ni < 4; ni++){
                int nn = n0 + wc*64 + ni*16 + l15;
                C[(size_t)mm * N + nn] = acc[mi][ni][jj] + bias[nn];
            }
        }
    }
}

// ---------------- gate (MFMA): g=sigmoid(Q @ Wg[h]); VgT[b,h,e,t] = g*v ----------------
__global__ __launch_bounds__(256) void gate_kernel(const ushortT* __restrict__ qkv,
                                                   const ushortT* __restrict__ WgT,
                                                   ushortT* __restrict__ vgT){
    __shared__ __align__(16) ushortT VT[64][72];
    int tblk = blockIdx.x, bh = blockIdx.y;
    int b = bh >> 4, h = bh & 15;
    int tid = threadIdx.x, wid = tid >> 6, lane = tid & 63;
    int l15 = lane & 15, g = lane >> 4;
    int t0 = tblk * 64;
    int tl = wid*16 + l15;

    const ushortT* qrow = qkv + ((size_t)b*T_SEQ + t0 + tl)*TD + h*DH;
    bf16x8 qf0 = *(const bf16x8*)(qrow + 8*g);
    bf16x8 qf1 = *(const bf16x8*)(qrow + 32 + 8*g);

    const ushortT* wbase = WgT + h*4096;
    const ushortT* vrow = qkv + ((size_t)b*T_SEQ + t0 + tl)*TD + 2*DM + h*DH;

#pragma unroll
    for (int ns = 0; ns < 4; ns++){
        int e = ns*16 + l15;
        bf16x8 wf0 = *(const bf16x8*)(wbase + e*64 + 8*g);
        bf16x8 wf1 = *(const bf16x8*)(wbase + e*64 + 32 + 8*g);
        f32x4 z = (f32x4){0.f,0.f,0.f,0.f};
        z = __builtin_amdgcn_mfma_f32_16x16x32_bf16(wf0, qf0, z, 0, 0, 0);
        z = __builtin_amdgcn_mfma_f32_16x16x32_bf16(wf1, qf1, z, 0, 0, 0);
        union { ushortT u[4]; uint2 v; } v4;
        v4.v = *(const uint2*)(vrow + ns*16 + 4*g);
#pragma unroll
        for (int jj = 0; jj < 4; jj++){
            float ex = __builtin_amdgcn_exp2f(-z[jj] * LOG2E);
            float gv = __builtin_amdgcn_rcpf(1.f + ex);
            VT[ns*16 + 4*g + jj][tl] = f2bf(gv * bf2f(v4.u[jj]));
        }
    }
    __syncthreads();
    for (int i = tid; i < 64*8; i += 256){
        int e = i >> 3, c8 = (i & 7) * 8;
        *(uint4*)&vgT[((size_t)bh * DH + e) * T_SEQ + t0 + c8] = *(const uint4*)&VT[e][c8];
    }
}

// ---------------- causal flash attention, KVBLK=128 joint softmax (R14 exact) ----------------
struct QS {
    bf16x8 qf0, qf1;
    float m_, lsum;
    f32x4 acc[4];          // acc[nt][jj] = O^T[e=nt*16+4g+jj][q=l15]
};

__device__ __forceinline__ void proc2(const ushortT* __restrict__ K0,
                                      const ushortT* __restrict__ V0,
                                      const ushortT* __restrict__ K1,
                                      const ushortT* __restrict__ V1,
                                      QS& S, int t0, int t1, int myp,
                                      int wq, int l15, int g){
    int l7 = l15 & 7;
    f32x4 s[8];
    __builtin_amdgcn_s_setprio(1);
#pragma unroll
    for (int ns = 0; ns < 4; ns++){
        int kr = ns*16 + l15;
        bf16x8 kf0 = *(const bf16x8*)(K0 + kr*64 + ((g    ) ^ l7)*8);
        bf16x8 kf1 = *(const bf16x8*)(K0 + kr*64 + ((4 + g) ^ l7)*8);
        f32x4 z = (f32x4){0.f,0.f,0.f,0.f};
        z = __builtin_amdgcn_mfma_f32_16x16x32_bf16(kf0, S.qf0, z, 0, 0, 0);
        z = __builtin_amdgcn_mfma_f32_16x16x32_bf16(kf1, S.qf1, z, 0, 0, 0);
        s[ns] = z;
    }
#pragma unroll
    for (int ns = 0; ns < 4; ns++){
        int kr = ns*16 + l15;
        bf16x8 kf0 = *(const bf16x8*)(K1 + kr*64 + ((g    ) ^ l7)*8);
        bf16x8 kf1 = *(const bf16x8*)(K1 + kr*64 + ((4 + g) ^ l7)*8);
        f32x4 z = (f32x4){0.f,0.f,0.f,0.f};
        z = __builtin_amdgcn_mfma_f32_16x16x32_bf16(kf0, S.qf0, z, 0, 0, 0);
        z = __builtin_amdgcn_mfma_f32_16x16x32_bf16(kf1, S.qf1, z, 0, 0, 0);
        s[4 + ns] = z;
    }
    __builtin_amdgcn_s_setprio(0);

    int qrel = wq*16 + l15;
    bool diag0 = (t0 == myp);
    bool inv1  = (t1 > myp);
    bool diag1 = (t1 == myp);
    if (diag0){
#pragma unroll
        for (int ns = 0; ns < 4; ns++){
            int kb = ((ns & 2) << 4) + 8*g + ((ns & 1) << 2);
#pragma unroll
            for (int jj = 0; jj < 4; jj++)
                if (kb + jj > qrel) s[ns][jj] = -INFINITY;
        }
    }
    if (inv1){
#pragma unroll
        for (int ns = 0; ns < 4; ns++)
#pragma unroll
            for (int jj = 0; jj < 4; jj++) s[4+ns][jj] = -INFINITY;
    } else if (diag1){
#pragma unroll
        for (int ns = 0; ns < 4; ns++){
            int kb = ((ns & 2) << 4) + 8*g + ((ns & 1) << 2);
#pragma unroll
            for (int jj = 0; jj < 4; jj++)
                if (kb + jj > qrel) s[4+ns][jj] = -INFINITY;
        }
    }

    float tmax = -INFINITY;
#pragma unroll
    for (int ns = 0; ns < 8; ns++){
        float a = fmaxf(s[ns][0], s[ns][1]);
        float c = fmaxf(s[ns][2], s[ns][3]);
        tmax = fmaxf(tmax, fmaxf(a, c));
    }
    tmax = fmaxf(tmax, __shfl_xor(tmax, 16, 64));
    tmax = fmaxf(tmax, __shfl_xor(tmax, 32, 64));

    float mnew = fmaxf(S.m_, tmax);
    float mc = mnew * LOG2E;
    float rs = 0.f;
    bf16x8 pa[4];
#pragma unroll
    for (int pr = 0; pr < 4; pr++){
#pragma unroll
        for (int jj = 0; jj < 4; jj++){
            float p0 = __builtin_amdgcn_exp2f(fmaf(s[2*pr  ][jj], LOG2E, -mc));
            float p1 = __builtin_amdgcn_exp2f(fmaf(s[2*pr+1][jj], LOG2E, -mc));
            rs += p0 + p1;
            pa[pr][jj]   = (__bf16)p0;
            pa[pr][4+jj] = (__bf16)p1;
        }
    }
    rs += __shfl_xor(rs, 16, 64);
    rs += __shfl_xor(rs, 32, 64);

    if (!__all(mnew == S.m_)){
        float alpha = __builtin_amdgcn_exp2f(fmaf(S.m_, LOG2E, -mc));
#pragma unroll
        for (int nt = 0; nt < 4; nt++)
#pragma unroll
            for (int jj = 0; jj < 4; jj++) S.acc[nt][jj] *= alpha;
        S.lsum *= alpha;
        S.m_ = mnew;
    }
    S.lsum += rs;

    __builtin_amdgcn_s_setprio(1);
#pragma unroll
    for (int ks = 0; ks < 2; ks++){
#pragma unroll
        for (int nt = 0; nt < 4; nt++){
            bf16x8 vf = *(const bf16x8*)(V0 + (nt*16 + l15)*64 + ((ks*4 + g) ^ l7)*8);
            S.acc[nt] = __builtin_amdgcn_mfma_f32_16x16x32_bf16(vf, pa[ks], S.acc[nt], 0, 0, 0);
        }
    }
    if (!inv1){
#pragma unroll
        for (int ks = 0; ks < 2; ks++){
#pragma unroll
            for (int nt = 0; nt < 4; nt++){
                bf16x8 vf = *(const bf16x8*)(V1 + (nt*16 + l15)*64 + ((ks*4 + g) ^ l7)*8);
                S.acc[nt] = __builtin_amdgcn_mfma_f32_16x16x32_bf16(vf, pa[2+ks], S.acc[nt], 0, 0, 0);
            }
        }
    }
    __builtin_amdgcn_s_setprio(0);
}

__global__ __launch_bounds__(512, 2) void attn_kernel(const ushortT* __restrict__ qkv,
                                                      const ushortT* __restrict__ vgT,
                                                      ushortT* __restrict__ obf){
    __shared__ __align__(16) ushortT Ks[2][2][64*64];   // [dbuf][tile] 32 KB
    __shared__ __align__(16) ushortT Vs[2][2][64*64];   // 32 KB
    int bh = blockIdx.x, y = blockIdx.y;
    int pairid = (y < 8) ? y : 23 - y;
    int b = bh >> 4, h = bh & 15;
    int tid = threadIdx.x, wid = tid >> 6, lane = tid & 63;
    int l15 = lane & 15, g = lane >> 4;
    int grp = wid >> 2;                     // 0: qblk pA, 1: qblk pB
    int wq  = wid & 3;

    const ushortT* Kg = qkv + (size_t)b * T_SEQ * TD + DM + h * DH;
    const ushortT* Vg = vgT + (size_t)bh * DH * T_SEQ;

    int pA = pairid, pB = 31 - pairid;
    int myp = grp ? pB : pA;

    int st_row  = tid >> 3;
    int st_c    = (tid & 7) ^ (st_row & 7);
    int st_prow = (st_row & 0x20) | ((st_row & 0x0C) << 1) |
                  ((st_row & 0x10) >> 2) | (st_row & 3);

#define STAGE_ROUND(buf, rr)                                                             \
    {                                                                                    \
        int t0_ = 2*(rr);     if (t0_ > pB) t0_ = pB;                                    \
        int t1_ = 2*(rr) + 1; if (t1_ > pB) t1_ = pB;                                    \
        gload_lds16(Kg + (size_t)(t0_*64 + st_prow) * TD + st_c*8,                       \
                    (char*)Ks[buf][0] + tid*16);                                         \
        gload_lds16(Kg + (size_t)(t1_*64 + st_prow) * TD + st_c*8,                       \
                    (char*)Ks[buf][1] + tid*16);                                         \
        gload_lds16(Vg + (size_t)st_row * T_SEQ + t0_*64 + st_c*8,                       \
                    (char*)Vs[buf][0] + tid*16);                                         \
        gload_lds16(Vg + (size_t)st_row * T_SEQ + t1_*64 + st_c*8,                       \
                    (char*)Vs[buf][1] + tid*16);                                         \
    }

    QS S;
    {
        int qrow = myp*64 + wq*16 + l15;
        const ushortT* qb = qkv + ((size_t)b * T_SEQ + qrow) * TD + h * DH;
        S.qf0 = *(const bf16x8*)(qb + 8*g);
        S.qf1 = *(const bf16x8*)(qb + 32 + 8*g);
#pragma unroll
        for (int j = 0; j < 8; j++){
            S.qf0[j] = (__bf16)((float)S.qf0[j] * 0.125f);
            S.qf1[j] = (__bf16)((float)S.qf1[j] * 0.125f);
        }
        S.m_ = -INFINITY; S.lsum = 0.f;
#pragma unroll
        for (int nt = 0; nt < 4; nt++) S.acc[nt] = (f32x4){0.f,0.f,0.f,0.f};
    }

    int nr = (33 - pairid) >> 1;            // ceil((pB+1)/2)
    STAGE_ROUND(0, 0);

    for (int r = 0; r < nr; r++){
        int buf = r & 1;
        BARRIER();                          // all waves done reading buf^1
        if (r + 1 < nr){
            STAGE_ROUND(buf ^ 1, r + 1);    // 4 loads stay in flight across barrier
            VMCNT(4);
        } else {
            VMCNT(0);
        }
        BARRIER();
        int t0 = 2*r;
        if (t0 <= myp)
            proc2(Ks[buf][0], Vs[buf][0], Ks[buf][1], Vs[buf][1],
                  S, t0, t0 + 1, myp, wq, l15, g);
    }
#undef STAGE_ROUND

    float inv = 1.f / S.lsum;
    size_t orow = ((size_t)b * T_SEQ + myp*64 + wq*16 + l15) * DM + h*DH;
#pragma unroll
    for (int nt = 0; nt < 4; nt++){
        union { ushortT u[4]; uint2 v; } pk;
#pragma unroll
        for (int jj = 0; jj < 4; jj++) pk.u[jj] = f2bf(S.acc[nt][jj] * inv);
        *(uint2*)&obf[orow + nt*16 + 4*g] = pk.v;
    }
}

extern "C" void kernel_launch(void* const* d_in, const int* in_sizes, int n_in,
                              void* d_out, int out_size, void* d_ws, size_t ws_size,
                              hipStream_t stream){
    const float* x    = (const float*)d_in[0];
    const float* Wqkv = (const float*)d_in[1];
    const float* bqkv = (const float*)d_in[2];
    const float* Wg   = (const float*)d_in[3];
    const float* Wout = (const float*)d_in[4];
    const float* bout = (const float*)d_in[5];

    char* ws = (char*)d_ws;
    ushortT* xbf   = (ushortT*)(ws);                 //  8 MB : (4096,1024) bf16
    ushortT* wqkvT = (ushortT*)(ws + 8388608);       //  6 MB : (3072,1024) bf16
    ushortT* woutT = (ushortT*)(ws + 14680064);      //  2 MB : (1024,1024) bf16
    ushortT* qkvb  = (ushortT*)(ws + 16777216);      // 24 MB : (4096,3072) bf16
    ushortT* vgT   = (ushortT*)(ws + 41943040);      //  8 MB : (32,64,2048) bf16
    ushortT* obf   = (ushortT*)(ws + 50331648);      //  8 MB : (4096,1024) bf16
    ushortT* wgT   = (ushortT*)(ws + 58720256);      // 128KB : (16,64,64) bf16

    prep_kernel<<<5136, 256, 0, stream>>>(x, xbf, Wqkv, wqkvT, Wout, woutT, Wg, wgT);
    gemm_bf16_kernel<<<dim3(32,24), 256, 0, stream>>>(xbf, wqkvT, bqkv, qkvb, 4096, 3072, 1024);
    gate_kernel<<<dim3(32,32), 256, 0, stream>>>(qkvb, wgT, vgT);
    attn_kernel<<<dim3(32,16), 512, 0, stream>>>(qkvb, vgT, obf);
    gemm_out_kernel<<<dim3(64,8), 256, 0, stream>>>(obf, woutT, bout, (float*)d_out, 4096, 1024, 1024);
}